// Round 4
// baseline (623.782 us; speedup 1.0000x reference)
//
#include <hip/hip_runtime.h>
#include <cstdint>
#include <cstddef>

typedef unsigned short ushort_t;
typedef unsigned int uint_t;

__device__ inline ushort_t f2bf(float f) {
  uint_t u = __float_as_uint(f);
  uint_t r = (u + 0x7fffu + ((u >> 16) & 1u)) >> 16;
  return (ushort_t)r;
}
__device__ inline float bfl(uint_t u) { return __uint_as_float(u << 16); }
__device__ inline float bfh(uint_t u) { return __uint_as_float(u & 0xffff0000u); }
__device__ inline float bf1(ushort_t v) { return __uint_as_float(((uint_t)v) << 16); }

// ---------------- CSR construction ----------------

__global__ void deg_kernel(const int* __restrict__ edst, int* __restrict__ deg, int E) {
  int i = blockIdx.x * 256 + threadIdx.x;
  if (i < E) atomicAdd(&deg[edst[i]], 1);
}

__global__ void chunk_sum_kernel(const int* __restrict__ deg, int* __restrict__ csum, int n) {
  __shared__ int wsum[16];
  int t = threadIdx.x;
  int i = blockIdx.x * 1024 + t;
  int v = (i < n) ? deg[i] : 0;
  for (int m = 1; m < 64; m <<= 1) v += __shfl_xor(v, m);
  if ((t & 63) == 0) wsum[t >> 6] = v;
  __syncthreads();
  if (t == 0) {
    int s = 0;
    for (int j = 0; j < 16; ++j) s += wsum[j];
    csum[blockIdx.x] = s;
  }
}

__global__ void scan_chunks_kernel(int* __restrict__ csum, int nchunks) {
  __shared__ int wsum[16];
  int t = threadIdx.x;
  int lane = t & 63, w = t >> 6;
  int x = (t < nchunks) ? csum[t] : 0;
  for (int off = 1; off < 64; off <<= 1) { int y = __shfl_up(x, off); if (lane >= off) x += y; }
  if (lane == 63) wsum[w] = x;
  __syncthreads();
  if (t < 16) {
    int s = wsum[t];
    for (int off = 1; off < 16; off <<= 1) { int y = __shfl_up(s, off); if (t >= off) s += y; }
    wsum[t] = s;
  }
  __syncthreads();
  if (w > 0) x += wsum[w - 1];
  if (t < nchunks) csum[t] = x;
}

__global__ void scan_final_kernel(const int* __restrict__ deg, const int* __restrict__ csum,
                                  int* __restrict__ rowptr, int n) {
  __shared__ int wsum[16];
  int t = threadIdx.x, b = blockIdx.x;
  int i = b * 1024 + t;
  int lane = t & 63, w = t >> 6;
  int x = (i < n) ? deg[i] : 0;
  for (int off = 1; off < 64; off <<= 1) { int y = __shfl_up(x, off); if (lane >= off) x += y; }
  if (lane == 63) wsum[w] = x;
  __syncthreads();
  if (t < 16) {
    int s = wsum[t];
    for (int off = 1; off < 16; off <<= 1) { int y = __shfl_up(s, off); if (t >= off) s += y; }
    wsum[t] = s;
  }
  __syncthreads();
  if (w > 0) x += wsum[w - 1];
  int off0 = (b > 0) ? csum[b - 1] : 0;
  if (i < n) rowptr[i + 1] = off0 + x;
  if (b == 0 && t == 0) rowptr[0] = 0;
}

__global__ void fill_kernel(const int* __restrict__ esrc, const int* __restrict__ edst,
                            const int* __restrict__ rowptr, int* __restrict__ fillc,
                            int* __restrict__ csr_src, int E) {
  int i = blockIdx.x * 256 + threadIdx.x;
  if (i < E) {
    int d = edst[i];
    int pos = atomicAdd(&fillc[d], 1);
    csr_src[rowptr[d] + pos] = esrc[i];
  }
}

// ---------------- GEMM1 + att1 fused: h1b(bf16) = x@W1; a_s/a_d dots (f32) ----------------
__global__ void gemm1_att1_kernel(const float* __restrict__ x, const float* __restrict__ W,
                                  const float* __restrict__ asw, const float* __restrict__ adw,
                                  ushort_t* __restrict__ h1b, float* __restrict__ a_s,
                                  float* __restrict__ a_d, int n) {
  __shared__ float wlds[128 * 128];
  int t = threadIdx.x;
  for (int i = t * 4; i < 128 * 128; i += 256 * 4)
    *(float4*)&wlds[i] = *(const float4*)&W[i];
  __syncthreads();
  int cg = t & 31, rg = t >> 5;
  int c0 = cg * 4;
  int row0 = blockIdx.x * 64 + rg * 8;
  float acc[8][4] = {};
  const float* xr[8];
  #pragma unroll
  for (int i = 0; i < 8; ++i) {
    int r = row0 + i;
    xr[i] = x + (size_t)(r < n ? r : 0) * 128;
  }
  #pragma unroll 4
  for (int k = 0; k < 128; ++k) {
    float4 w4 = *(float4*)&wlds[k * 128 + c0];
    #pragma unroll
    for (int i = 0; i < 8; ++i) {
      float xv = xr[i][k];
      acc[i][0] += xv * w4.x; acc[i][1] += xv * w4.y;
      acc[i][2] += xv * w4.z; acc[i][3] += xv * w4.w;
    }
  }
  float4 as4 = *(const float4*)&asw[c0];
  float4 ad4 = *(const float4*)&adw[c0];
  int hd = cg >> 2;
  bool leader = (cg & 3) == 0;
  #pragma unroll
  for (int i = 0; i < 8; ++i) {
    int r = row0 + i;
    float ps = acc[i][0] * as4.x + acc[i][1] * as4.y + acc[i][2] * as4.z + acc[i][3] * as4.w;
    float pd = acc[i][0] * ad4.x + acc[i][1] * ad4.y + acc[i][2] * ad4.z + acc[i][3] * ad4.w;
    ps += __shfl_xor(ps, 1); ps += __shfl_xor(ps, 2);
    pd += __shfl_xor(pd, 1); pd += __shfl_xor(pd, 2);
    if (r < n) {
      ushort_t hb4[4] = { f2bf(acc[i][0]), f2bf(acc[i][1]), f2bf(acc[i][2]), f2bf(acc[i][3]) };
      *(uint2*)&h1b[(size_t)r * 128 + c0] = *(uint2*)hb4;
      if (leader) {
        a_s[(size_t)r * 8 + hd] = ps;
        a_d[(size_t)r * 8 + hd] = pd;
      }
    }
  }
}

// ---------------- GAT layer 1 aggregate: one wave per dst ----------------
__global__ void gat1_agg_kernel(const int* __restrict__ rowptr, const int* __restrict__ csr_src,
                                const ushort_t* __restrict__ h1b,
                                const float* __restrict__ a_s, const float* __restrict__ a_d,
                                const float* __restrict__ b1, float* __restrict__ hmid, int n) {
  __shared__ float pl[4][64][8];
  int t = threadIdx.x & 63;
  int w = threadIdx.x >> 6;
  int dst = blockIdx.x * 4 + w;
  if (dst >= n) return;
  int beg = rowptr[dst], end = rowptr[dst + 1];
  int hh = t >> 3;

  float4 ad0 = *(const float4*)&a_d[(size_t)dst * 8];
  float4 ad1 = *(const float4*)&a_d[(size_t)dst * 8 + 4];
  float adv[8] = { ad0.x, ad0.y, ad0.z, ad0.w, ad1.x, ad1.y, ad1.z, ad1.w };

  float M[8], S[8];
  #pragma unroll
  for (int h = 0; h < 8; ++h) { M[h] = -1e30f; S[h] = 0.f; }
  float acc0 = 0.f, acc1 = 0.f;

  for (int base = beg; base < end; base += 64) {
    int eidx = base + t;
    bool valid = eidx < end;
    int s = csr_src[valid ? eidx : beg];
    const float4* ap = (const float4*)(a_s + (size_t)s * 8);
    float4 A0 = ap[0], A1 = ap[1];
    float ev[8] = { A0.x + adv[0], A0.y + adv[1], A0.z + adv[2], A0.w + adv[3],
                    A1.x + adv[4], A1.y + adv[5], A1.z + adv[6], A1.w + adv[7] };
    float e[8];
    #pragma unroll
    for (int h = 0; h < 8; ++h) {
      float u = ev[h];
      u = u > 0.f ? u : 0.2f * u;
      e[h] = valid ? u : -1e30f;
    }
    float scl = 1.f;
    #pragma unroll
    for (int h = 0; h < 8; ++h) {
      float m = e[h];
      #pragma unroll
      for (int o = 1; o < 64; o <<= 1) m = fmaxf(m, __shfl_xor(m, o));
      float nm = fmaxf(M[h], m);
      float p = valid ? __expf(e[h] - nm) : 0.f;
      float psum = p;
      #pragma unroll
      for (int o = 1; o < 64; o <<= 1) psum += __shfl_xor(psum, o);
      float sc = __expf(M[h] - nm);
      S[h] = S[h] * sc + psum;
      M[h] = nm;
      if (hh == h) scl = sc;
      pl[w][t][h] = p;
    }
    acc0 *= scl; acc1 *= scl;
    int cnt = min(64, end - base);
    for (int i = 0; i < cnt; ++i) {
      int si = __shfl(s, i);
      float pi = pl[w][i][hh];
      uint_t hv = *(const uint_t*)(h1b + (size_t)si * 128 + 2 * t);
      acc0 = fmaf(pi, bfl(hv), acc0);
      acc1 = fmaf(pi, bfh(hv), acc1);
    }
  }

  float Sfin = S[0];
  #pragma unroll
  for (int h = 1; h < 8; ++h) if (hh == h) Sfin = S[h];
  float inv = 1.f / (Sfin + 1e-16f);
  float2 b = *(const float2*)&b1[2 * t];
  float v0 = acc0 * inv + b.x;
  float v1 = acc1 * inv + b.y;
  v0 = v0 > 0.f ? v0 : (__expf(v0) - 1.f);
  v1 = v1 > 0.f ? v1 : (__expf(v1) - 1.f);
  float2 o = { v0, v1 };
  *(float2*)&hmid[(size_t)dst * 128 + 2 * t] = o;
}

// ---------------- GEMM2 + att2 fused: h2b(bf16) = hmid @ W2; a_s2/a_d2 (f32) ----------------
__global__ void gemm2_att2_kernel(const float* __restrict__ hmid, const float* __restrict__ W2,
                                  const float* __restrict__ asw, const float* __restrict__ adw,
                                  ushort_t* __restrict__ h2b, float* __restrict__ a_s2,
                                  float* __restrict__ a_d2, int n) {
  __shared__ float w[128 * 16];
  int t = threadIdx.x;
  for (int i = t; i < 128 * 16; i += 256) w[i] = W2[i];
  __syncthreads();
  int gid = blockIdx.x * 256 + t;
  int node = gid >> 4, c = gid & 15;
  if (node >= n) return;
  const float* row = &hmid[(size_t)node * 128];
  float acc = 0.f;
  #pragma unroll 4
  for (int k = 0; k < 128; ++k) acc += row[k] * w[k * 16 + c];
  h2b[(size_t)node * 16 + c] = f2bf(acc);
  float ps = acc * asw[c], pd = acc * adw[c];
  #pragma unroll
  for (int m = 1; m < 16; m <<= 1) { ps += __shfl_xor(ps, m); pd += __shfl_xor(pd, m); }
  if (c == 0) { a_s2[node] = ps; a_d2[node] = pd; }
}

// ---------------- GAT layer 2 aggregate + pooled atomics ----------------
__global__ void gat2_agg_kernel(const int* __restrict__ rowptr, const int* __restrict__ csr_src,
                                const ushort_t* __restrict__ h2b, const float* __restrict__ a_s2,
                                const float* __restrict__ a_d2, const float* __restrict__ b2,
                                const int* __restrict__ batch,
                                float* __restrict__ pooled, float* __restrict__ cntb,
                                int n, int G) {
  __shared__ float pooledL[17][16];
  __shared__ float cntL[17];
  int t = threadIdx.x;
  if (t < 17) cntL[t] = 0.f;
  for (int i = t; i < 17 * 16; i += 256) ((float*)pooledL)[i] = 0.f;
  __syncthreads();

  int grp = t >> 4, c = t & 15;
  int dst = blockIdx.x * 16 + grp;
  int gfirst = batch[blockIdx.x * 16];

  if (dst < n) {
    int beg = rowptr[dst], end = rowptr[dst + 1];
    int deg = end - beg;
    float M = -1e30f, S = 0.f, acc = 0.f;
    float adv = a_d2[dst];

    for (int base = 0; base < deg; base += 16) {
      int cnt = min(16, deg - base);
      int s = 0; float e = -1e30f;
      if (c < cnt) {
        s = csr_src[beg + base + c];
        float ev = a_s2[s] + adv;
        e = ev > 0.f ? ev : 0.2f * ev;
      }
      float cm = e;
      #pragma unroll
      for (int m = 1; m < 16; m <<= 1) cm = fmaxf(cm, __shfl_xor(cm, m));
      float newM = fmaxf(M, cm);
      float p = (c < cnt) ? __expf(e - newM) : 0.f;
      float ss = p;
      #pragma unroll
      for (int m = 1; m < 16; m <<= 1) ss += __shfl_xor(ss, m);
      float sc = __expf(M - newM);
      S = S * sc + ss;
      M = newM;
      acc *= sc;
      #pragma unroll
      for (int i = 0; i < 16; ++i) {
        float pi = __shfl(p, i, 16);
        int   si = __shfl(s, i, 16);
        acc = fmaf(pi, bf1(h2b[(size_t)si * 16 + c]), acc);
      }
    }

    float v = acc / (S + 1e-16f) + b2[c];
    int g = batch[dst];
    int gi = g - gfirst;
    if (gi <= 16) {
      atomicAdd(&pooledL[gi][c], v);
      if (c == 0) atomicAdd(&cntL[gi], 1.f);
    } else {
      atomicAdd(&pooled[g * 16 + c], v);
      if (c == 0) atomicAdd(&cntb[g], 1.f);
    }
  }
  __syncthreads();

  int w = t >> 5, lane32 = t & 31;
  for (int gi = w; gi < 17; gi += 8) {
    if (cntL[gi] > 0.f) {
      int g = gfirst + gi;
      if (lane32 < 16) atomicAdd(&pooled[g * 16 + lane32], pooledL[gi][lane32]);
      else if (lane32 == 16) atomicAdd(&cntb[g], cntL[gi]);
    }
  }
}

// ---------------- final: mean + log_softmax ----------------
__global__ void final_kernel(const float* __restrict__ pooled, const float* __restrict__ cntb,
                             float* __restrict__ out, int G) {
  int g = threadIdx.x;
  if (g >= G) return;
  float c = fmaxf(cntb[g], 1.f);
  float v[16];
  float m = -1e30f;
  #pragma unroll
  for (int i = 0; i < 16; ++i) { v[i] = pooled[g * 16 + i] / c; m = fmaxf(m, v[i]); }
  float s = 0.f;
  #pragma unroll
  for (int i = 0; i < 16; ++i) s += __expf(v[i] - m);
  float ls = logf(s);
  #pragma unroll
  for (int i = 0; i < 16; ++i) out[g * 16 + i] = v[i] - m - ls;
}

// ---------------- launcher ----------------
extern "C" void kernel_launch(void* const* d_in, const int* in_sizes, int n_in,
                              void* d_out, int out_size, void* d_ws, size_t ws_size,
                              hipStream_t stream) {
  const float* x    = (const float*)d_in[0];
  const int*   eidx = (const int*)  d_in[1];
  const int*   batch= (const int*)  d_in[2];
  const float* W1   = (const float*)d_in[3];
  const float* as1w = (const float*)d_in[4];
  const float* ad1w = (const float*)d_in[5];
  const float* b1   = (const float*)d_in[6];
  const float* W2   = (const float*)d_in[7];
  const float* as2w = (const float*)d_in[8];
  const float* ad2w = (const float*)d_in[9];
  const float* b2   = (const float*)d_in[10];
  float* out = (float*)d_out;

  int N = in_sizes[0] / 128;
  int E = in_sizes[1] / 2;
  int G = out_size / 16;
  const int* esrc = eidx;
  const int* edst = eidx + E;

  char* p = (char*)d_ws;
  auto alloc = [&](size_t bytes) {
    char* r = p;
    p += (bytes + 255) & ~(size_t)255;
    return r;
  };
  ushort_t* h1b = (ushort_t*)alloc((size_t)N * 128 * 2);
  float* hmid = (float*)alloc((size_t)N * 128 * 4);
  ushort_t* h2b = (ushort_t*)alloc((size_t)N * 16 * 2);
  float* as1  = (float*)alloc((size_t)N * 8 * 4);
  float* ad1  = (float*)alloc((size_t)N * 8 * 4);
  float* as2  = (float*)alloc((size_t)N * 4);
  float* ad2  = (float*)alloc((size_t)N * 4);
  float* pooled = (float*)alloc((size_t)(G * 16 + G) * 4);
  float* cntb = pooled + G * 16;
  int* deg    = (int*)alloc((size_t)N * 4);
  int* rowptr = (int*)alloc((size_t)(N + 1) * 4);
  int* fillc  = (int*)alloc((size_t)N * 4);
  int* csr    = (int*)alloc((size_t)E * 4);
  int* csum   = (int*)alloc(1024 * 4);

  hipMemsetAsync(deg, 0, (size_t)N * 4, stream);
  hipMemsetAsync(fillc, 0, (size_t)N * 4, stream);
  hipMemsetAsync(pooled, 0, (size_t)(G * 16 + G) * 4, stream);

  int nchunks = (N + 1023) / 1024;
  deg_kernel<<<(E + 255) / 256, 256, 0, stream>>>(edst, deg, E);
  chunk_sum_kernel<<<nchunks, 1024, 0, stream>>>(deg, csum, N);
  scan_chunks_kernel<<<1, 1024, 0, stream>>>(csum, nchunks);
  scan_final_kernel<<<nchunks, 1024, 0, stream>>>(deg, csum, rowptr, N);
  fill_kernel<<<(E + 255) / 256, 256, 0, stream>>>(esrc, edst, rowptr, fillc, csr, E);

  gemm1_att1_kernel<<<(N + 63) / 64, 256, 0, stream>>>(x, W1, as1w, ad1w, h1b, as1, ad1, N);
  gat1_agg_kernel<<<(N + 3) / 4, 256, 0, stream>>>(rowptr, csr, h1b, as1, ad1, b1, hmid, N);
  gemm2_att2_kernel<<<(N * 16 + 255) / 256, 256, 0, stream>>>(hmid, W2, as2w, ad2w, h2b, as2, ad2, N);
  gat2_agg_kernel<<<(N + 15) / 16, 256, 0, stream>>>(rowptr, csr, h2b, as2, ad2, b2, batch, pooled, cntb, N, G);
  final_kernel<<<1, (G + 63) / 64 * 64, 0, stream>>>(pooled, cntb, out, G);
}